// Round 7
// baseline (239.425 us; speedup 1.0000x reference)
//
#include <hip/hip_runtime.h>

#define B_ 16
#define C_ 256
#define N_ 16384      // 128*128
#define R_ 16
#define SUB_ 32       // n per subtile

typedef float f32x4 __attribute__((ext_vector_type(4)));

// ---------------------------------------------------------------------------
// kA: fused stats pass, register-resident (no x tile in LDS).
// Thread (kq=t&7, crow=t>>3) owns n-slots {4kq..4kq+3} of each subtile and
// channels {crow+32r, r=0..7} held in pre[8] (float4 each).
//   colsum: per-thread 8-channel partial (VALU) -> shfl_xor over lane bits
//   3/4/5 (the crow-within-wave axis) -> one f4 LDS write per 8 lanes ->
//   tiny cross-wave reduce -> colsum[32].
//   accP[r] += pre[r] . colsum[4kq..4kq+3];  accRS[r] += sum(pre[r]).
// End: shfl_xor over kq lanes (bits 0/1/2) -> per-channel partials out.
// ~6 LDS ops + 2 barriers per subtile (vs 96+3 in R4); LDS < 1 KiB.
// ---------------------------------------------------------------------------
template<int NSUB>
__global__ void kA(const float* __restrict__ x,
                   float* __restrict__ Ppart,
                   float* __restrict__ RSpart,
                   int blocksPerBatch) {
    const int blk = blockIdx.x;
    const int b = blockIdx.y;
    const int t = threadIdx.x;
    const int kq = t & 7;       // n-group (4 floats)
    const int crow = t >> 3;    // 0..31
    const int wave = t >> 6;    // 0..3
    const int lane = t & 63;

    __shared__ float csum_w[4][8][4];   // [wave][kq][j]
    __shared__ float colsum[SUB_];

    const float* xb = x + (size_t)b * C_ * N_
                    + (size_t)blk * (NSUB * SUB_) + (kq << 2);

    float accP[8], accRS[8];
#pragma unroll
    for (int r = 0; r < 8; ++r) { accP[r] = 0.f; accRS[r] = 0.f; }

    for (int s = 0; s < NSUB; ++s) {
        const int n0 = s * SUB_;
        float4 pre[8];
#pragma unroll
        for (int r = 0; r < 8; ++r)
            pre[r] = *reinterpret_cast<const float4*>(
                xb + (size_t)(crow + (r << 5)) * N_ + n0);

        // per-thread channel-partial for its 4 n-slots
        float4 cs = pre[0];
#pragma unroll
        for (int r = 1; r < 8; ++r) {
            cs.x += pre[r].x; cs.y += pre[r].y;
            cs.z += pre[r].z; cs.w += pre[r].w;
        }
        // reduce over the 8 crow-lanes of this wave (lane bits 3,4,5)
#pragma unroll
        for (int m = 8; m <= 32; m <<= 1) {
            cs.x += __shfl_xor(cs.x, m, 64);
            cs.y += __shfl_xor(cs.y, m, 64);
            cs.z += __shfl_xor(cs.z, m, 64);
            cs.w += __shfl_xor(cs.w, m, 64);
        }
        if (lane < 8)
            *reinterpret_cast<float4*>(&csum_w[wave][kq][0]) =
                make_float4(cs.x, cs.y, cs.z, cs.w);
        __syncthreads();
        if (t < SUB_)
            colsum[t] = csum_w[0][t >> 2][t & 3] + csum_w[1][t >> 2][t & 3]
                      + csum_w[2][t >> 2][t & 3] + csum_w[3][t >> 2][t & 3];
        __syncthreads();

        const float4 cl = *reinterpret_cast<const float4*>(&colsum[kq << 2]);
#pragma unroll
        for (int r = 0; r < 8; ++r) {
            accP[r] += pre[r].x * cl.x + pre[r].y * cl.y
                     + pre[r].z * cl.z + pre[r].w * cl.w;
            accRS[r] += pre[r].x + pre[r].y + pre[r].z + pre[r].w;
        }
    }

    // fold the 8 kq-lanes (bits 0,1,2) -> full block-partial per channel
#pragma unroll
    for (int r = 0; r < 8; ++r) {
#pragma unroll
        for (int m = 1; m <= 4; m <<= 1) {
            accP[r]  += __shfl_xor(accP[r],  m, 64);
            accRS[r] += __shfl_xor(accRS[r], m, 64);
        }
    }
    if (kq == 0) {
        const size_t base = ((size_t)b * blocksPerBatch + blk) * C_;
#pragma unroll
        for (int r = 0; r < 8; ++r) {
            Ppart [base + crow + (r << 5)] = accP[r];
            RSpart[base + crow + (r << 5)] = accRS[r];
        }
    }
}

// ---------------------------------------------------------------------------
// kB: reduce partials -> v -> fused MLP -> gate.  grid(B_) x 256, thread = c.
// ---------------------------------------------------------------------------
__global__ void kB(const float* __restrict__ Ppart,
                   const float* __restrict__ RSpart,
                   const float* __restrict__ w1, const float* __restrict__ b1,
                   const float* __restrict__ w2, const float* __restrict__ b2,
                   float* __restrict__ gate, int blocksPerBatch) {
    const int b = blockIdx.x;
    const int t = threadIdx.x;   // channel c

    float P = 0.f, RS = 0.f;
    for (int k = 0; k < blocksPerBatch; ++k) {
        P  += Ppart [((size_t)b * blocksPerBatch + k) * C_ + t];
        RS += RSpart[((size_t)b * blocksPerBatch + k) * C_ + t];
    }

    __shared__ float red[4];
    float s = RS;
#pragma unroll
    for (int off = 32; off; off >>= 1) s += __shfl_down(s, off, 64);
    if ((t & 63) == 0) red[t >> 6] = s;
    __syncthreads();
    const float T = red[0] + red[1] + red[2] + red[3];
    const float M = T / (float)N_;
    const float denom = (float)(N_ - 1) * (float)C_;

    __shared__ float vl[C_];
    vl[t] = (P - M * RS) / denom;
    __syncthreads();

    __shared__ float hpart[R_][16];
    __shared__ float h1[R_];
    {
        const int i = t >> 4, cc = t & 15;
        float a = 0.f;
#pragma unroll
        for (int k = 0; k < 16; ++k)
            a += vl[(cc << 4) + k] * w1[i * C_ + (cc << 4) + k];
        hpart[i][cc] = a;
    }
    __syncthreads();
    if (t < R_) {
        float a = b1[t];
#pragma unroll
        for (int k = 0; k < 16; ++k) a += hpart[t][k];
        h1[t] = a > 0.f ? a : 0.f;
    }
    __syncthreads();

    float a = b2[t];
#pragma unroll
    for (int i = 0; i < R_; ++i) a += h1[i] * w2[t * R_ + i];
    gate[b * C_ + t] = 1.f / (1.f + __expf(-a));
}

// ---------------------------------------------------------------------------
// kC: out = x * gate[b,c].  x read normally (L3 hits from kA's warm);
// out written non-temporally (nt -> LLC no-allocate) so x stays resident.
// ---------------------------------------------------------------------------
__global__ void kC(const float* __restrict__ x,
                   const float* __restrict__ gate,
                   float* __restrict__ out) {
    const size_t total4 = (size_t)B_ * C_ * N_ / 4;
    for (size_t i = (size_t)blockIdx.x * blockDim.x + threadIdx.x; i < total4;
         i += (size_t)gridDim.x * blockDim.x) {
        const int bc = (int)(i >> 12);           // N_/4 = 4096 float4 per (b,c)
        const float g = gate[bc];
        float4 vx = reinterpret_cast<const float4*>(x)[i];
        f32x4 r;
        r.x = vx.x * g; r.y = vx.y * g; r.z = vx.z * g; r.w = vx.w * g;
        __builtin_nontemporal_store(r, reinterpret_cast<f32x4*>(out) + i);
    }
}

extern "C" void kernel_launch(void* const* d_in, const int* in_sizes, int n_in,
                              void* d_out, int out_size, void* d_ws, size_t ws_size,
                              hipStream_t stream) {
    (void)in_sizes; (void)n_in; (void)out_size;
    const float* x  = (const float*)d_in[0];
    const float* w1 = (const float*)d_in[1];
    const float* b1 = (const float*)d_in[2];
    const float* w2 = (const float*)d_in[3];
    const float* b2 = (const float*)d_in[4];
    float* out = (float*)d_out;

    const size_t need64 = (size_t)(2 * B_ * 64 * C_ + B_ * C_) * sizeof(float);
    const int bpb = (ws_size >= need64) ? 64 : 32;   // blocks per batch

    float* ws     = (float*)d_ws;
    float* Ppart  = ws;                                    // B_*bpb*C_
    float* RSpart = Ppart + (size_t)B_ * bpb * C_;         // B_*bpb*C_
    float* gate   = RSpart + (size_t)B_ * bpb * C_;        // B_*C_

    if (bpb == 64) {
        hipLaunchKernelGGL((kA<8>), dim3(64, B_), dim3(256), 0, stream,
                           x, Ppart, RSpart, 64);
    } else {
        hipLaunchKernelGGL((kA<16>), dim3(32, B_), dim3(256), 0, stream,
                           x, Ppart, RSpart, 32);
    }
    hipLaunchKernelGGL(kB, dim3(B_), dim3(256), 0, stream,
                       Ppart, RSpart, w1, b1, w2, b2, gate, bpb);
    hipLaunchKernelGGL(kC, dim3(2048), dim3(256), 0, stream,
                       x, gate, out);
}

// Round 8
// 157.754 us; speedup vs baseline: 1.5177x; 1.5177x over previous
//
#include <hip/hip_runtime.h>

#define B_ 16
#define C_ 256
#define N_ 16384      // 128*128
#define R_ 16
#define SUB_ 32       // n per subtile

typedef float f32x4 __attribute__((ext_vector_type(4)));

__device__ __forceinline__ float4 ldf4(const float* p) {
    return *reinterpret_cast<const float4*>(p);
}

// ---------------------------------------------------------------------------
// kA: fused stats pass (R4 structure) + counted-vmcnt pipeline.
// Per 32-n subtile: stage x[b, :, n0:n0+32] in LDS [c][33], colsum over c,
// accP[c] += x*colsum, accRS[c] += x.  Subtile s+1's 8 global loads are
// issued BEFORE staging s (ping-pong regs), and all barriers are RAW
// s_barrier with lgkmcnt-only waits -> loads stay in flight across the
// whole compute tail (no vmcnt(0) drain, the R5/R7 killer).
// LDS ~35 KiB -> 4 blocks/CU.  4 barriers per subtile, race-checked.
// ---------------------------------------------------------------------------
template<int NSUB>
__global__ __launch_bounds__(256)
void kA(const float* __restrict__ x,
        float* __restrict__ Ppart,
        float* __restrict__ RSpart,
        int blocksPerBatch) {
    const int blk = blockIdx.x;
    const int b = blockIdx.y;
    const int t = threadIdx.x;
    const int kq = t & 7;      // float4 slot within the 32-n row (0..7)
    const int crow = t >> 3;   // base channel row (0..31)

    __shared__ float tile[C_][33];     // [c][n] padded: all phases <=2-way
    __shared__ float csp[8][32];       // colsum partials [oct][n]
    __shared__ float colsum[SUB_];

    const float* xb = x + (size_t)b * C_ * N_
                    + (size_t)blk * (NSUB * SUB_) + (kq << 2);

    float4 pA[8], pB[8];
    float accP = 0.f, accRS = 0.f;

#pragma unroll
    for (int r = 0; r < 8; ++r)
        pA[r] = ldf4(xb + (size_t)(crow + (r << 5)) * N_);

#define PHASE(CUR, NXT, S)                                                     \
    {                                                                          \
        /* issue next subtile's loads FIRST -> stage wait is vmcnt(8) */       \
        if ((S) + 1 < NSUB) {                                                  \
            _Pragma("unroll")                                                  \
            for (int r = 0; r < 8; ++r)                                        \
                NXT[r] = ldf4(xb + (size_t)(crow + (r << 5)) * N_              \
                              + ((S) + 1) * SUB_);                             \
        }                                                                      \
        _Pragma("unroll")                                                      \
        for (int r = 0; r < 8; ++r)                                            \
            *reinterpret_cast<float4*>(&tile[crow + (r << 5)][kq << 2]) = CUR[r]; \
        asm volatile("s_waitcnt lgkmcnt(0)" ::: "memory");                     \
        __builtin_amdgcn_s_barrier();                                          \
        { /* colsum partials: thread (n=t&31, oct=t>>5) sums 32 channels */    \
            const int n = t & 31, oct = t >> 5;                                \
            float cs = 0.f;                                                    \
            _Pragma("unroll")                                                  \
            for (int i = 0; i < 32; ++i) cs += tile[(oct << 5) + i][n];        \
            csp[oct][n] = cs;                                                  \
        }                                                                      \
        asm volatile("s_waitcnt lgkmcnt(0)" ::: "memory");                     \
        __builtin_amdgcn_s_barrier();                                          \
        if (t < SUB_) {                                                        \
            float cs = 0.f;                                                    \
            _Pragma("unroll")                                                  \
            for (int o = 0; o < 8; ++o) cs += csp[o][t];                       \
            colsum[t] = cs;                                                    \
        }                                                                      \
        asm volatile("s_waitcnt lgkmcnt(0)" ::: "memory");                     \
        __builtin_amdgcn_s_barrier();                                          \
        _Pragma("unroll")                                                      \
        for (int j = 0; j < 8; ++j) { /* thread owns channel c = t */          \
            float4 xv = *reinterpret_cast<float4*>(&tile[t][j << 2]);          \
            float4 cl = *reinterpret_cast<float4*>(&colsum[j << 2]);           \
            accP += xv.x * cl.x + xv.y * cl.y + xv.z * cl.z + xv.w * cl.w;     \
            accRS += xv.x + xv.y + xv.z + xv.w;                                \
        }                                                                      \
        __builtin_amdgcn_s_barrier(); /* tile reads done before next stage */  \
    }

    for (int s = 0; s < NSUB; s += 2) {
        PHASE(pA, pB, s)
        PHASE(pB, pA, s + 1)
    }
#undef PHASE

    const size_t base = ((size_t)b * blocksPerBatch + blk) * C_;
    Ppart [base + t] = accP;
    RSpart[base + t] = accRS;
}

// ---------------------------------------------------------------------------
// kB: reduce partials -> v -> fused MLP -> gate.  grid(B_) x 256, thread = c.
// ---------------------------------------------------------------------------
__global__ void kB(const float* __restrict__ Ppart,
                   const float* __restrict__ RSpart,
                   const float* __restrict__ w1, const float* __restrict__ b1,
                   const float* __restrict__ w2, const float* __restrict__ b2,
                   float* __restrict__ gate, int blocksPerBatch) {
    const int b = blockIdx.x;
    const int t = threadIdx.x;   // channel c

    float P = 0.f, RS = 0.f;
    for (int k = 0; k < blocksPerBatch; ++k) {
        P  += Ppart [((size_t)b * blocksPerBatch + k) * C_ + t];
        RS += RSpart[((size_t)b * blocksPerBatch + k) * C_ + t];
    }

    __shared__ float red[4];
    float s = RS;
#pragma unroll
    for (int off = 32; off; off >>= 1) s += __shfl_down(s, off, 64);
    if ((t & 63) == 0) red[t >> 6] = s;
    __syncthreads();
    const float T = red[0] + red[1] + red[2] + red[3];
    const float M = T / (float)N_;
    const float denom = (float)(N_ - 1) * (float)C_;

    __shared__ float vl[C_];
    vl[t] = (P - M * RS) / denom;
    __syncthreads();

    __shared__ float hpart[R_][16];
    __shared__ float h1[R_];
    {
        const int i = t >> 4, cc = t & 15;
        float a = 0.f;
#pragma unroll
        for (int k = 0; k < 16; ++k)
            a += vl[(cc << 4) + k] * w1[i * C_ + (cc << 4) + k];
        hpart[i][cc] = a;
    }
    __syncthreads();
    if (t < R_) {
        float a = b1[t];
#pragma unroll
        for (int k = 0; k < 16; ++k) a += hpart[t][k];
        h1[t] = a > 0.f ? a : 0.f;
    }
    __syncthreads();

    float a = b2[t];
#pragma unroll
    for (int i = 0; i < R_; ++i) a += h1[i] * w2[t * R_ + i];
    gate[b * C_ + t] = 1.f / (1.f + __expf(-a));
}

// ---------------------------------------------------------------------------
// kC: out = x * gate[b,c]; nt stores (proven R4 config).
// ---------------------------------------------------------------------------
__global__ void kC(const float* __restrict__ x,
                   const float* __restrict__ gate,
                   float* __restrict__ out) {
    const size_t total4 = (size_t)B_ * C_ * N_ / 4;
    for (size_t i = (size_t)blockIdx.x * blockDim.x + threadIdx.x; i < total4;
         i += (size_t)gridDim.x * blockDim.x) {
        const int bc = (int)(i >> 12);           // N_/4 = 4096 float4 per (b,c)
        const float g = gate[bc];
        float4 vx = reinterpret_cast<const float4*>(x)[i];
        f32x4 r;
        r.x = vx.x * g; r.y = vx.y * g; r.z = vx.z * g; r.w = vx.w * g;
        __builtin_nontemporal_store(r, reinterpret_cast<f32x4*>(out) + i);
    }
}

extern "C" void kernel_launch(void* const* d_in, const int* in_sizes, int n_in,
                              void* d_out, int out_size, void* d_ws, size_t ws_size,
                              hipStream_t stream) {
    (void)in_sizes; (void)n_in; (void)out_size; (void)ws_size;
    const float* x  = (const float*)d_in[0];
    const float* w1 = (const float*)d_in[1];
    const float* b1 = (const float*)d_in[2];
    const float* w2 = (const float*)d_in[3];
    const float* b2 = (const float*)d_in[4];
    float* out = (float*)d_out;

    const int bpb = 64;   // blocks per batch (ws proven sufficient in R2-R7)

    float* ws     = (float*)d_ws;
    float* Ppart  = ws;                                    // B_*bpb*C_
    float* RSpart = Ppart + (size_t)B_ * bpb * C_;         // B_*bpb*C_
    float* gate   = RSpart + (size_t)B_ * bpb * C_;        // B_*C_

    hipLaunchKernelGGL((kA<8>), dim3(bpb, B_), dim3(256), 0, stream,
                       x, Ppart, RSpart, bpb);
    hipLaunchKernelGGL(kB, dim3(B_), dim3(256), 0, stream,
                       Ppart, RSpart, w1, b1, w2, b2, gate, bpb);
    hipLaunchKernelGGL(kC, dim3(2048), dim3(256), 0, stream,
                       x, gate, out);
}